// Round 6
// baseline (304.643 us; speedup 1.0000x reference)
//
#include <hip/hip_runtime.h>
#include <hip/hip_bf16.h>
#include <stdint.h>

// Problem dims: B=4, S=2048 -> M=8192; IN=K=4096; OUT=N=4096; R=16
#define M_DIM 8192
#define N_DIM 4096
#define K_DIM 4096
#define R_DIM 16

typedef __bf16 bf16x8 __attribute__((ext_vector_type(8)));
typedef float f32x4 __attribute__((ext_vector_type(4)));
typedef unsigned short u16x8 __attribute__((ext_vector_type(8)));

#define AS1(p) ((const __attribute__((address_space(1))) void*)(p))
#define AS3(p) ((__attribute__((address_space(3))) void*)(p))

// Clobber-free sync (m201 template): raw s_barrier (no drain), counted
// s_waitcnt without "memory" clobber (a clobber marks the asm mayLoad/mayStore
// and the waitcnt pass force-drains at barriers, reducing to drain-0 = the
// m218 V1 regime). sched_barrier(0) after lgkm0 pins MFMA below it (rule 18).
#define BAR()    __builtin_amdgcn_s_barrier()
#define LGKM0()  asm volatile("s_waitcnt lgkmcnt(0)")
#define LGKM8()  asm volatile("s_waitcnt lgkmcnt(8)")
#define VMCNT6() asm volatile("s_waitcnt vmcnt(6)")
#define VMCNT0() asm volatile("s_waitcnt vmcnt(0)")
#define SCHED0() __builtin_amdgcn_sched_barrier(0)

__device__ __forceinline__ unsigned short f2bf(float f) {
  unsigned u = __builtin_bit_cast(unsigned, f);
  u += 0x7FFFu + ((u >> 16) & 1u);   // round-to-nearest-even
  return (unsigned short)(u >> 16);
}

// ---------------------------------------------------------------------------
// prep: blocks [0,1024): awb[o,i] = bf16(W[o,i]*(1+sum_r A[r,i]*B[o,r]))
//       blocks [1024,5120): xb = bf16(x), vectorized grid-stride
// ---------------------------------------------------------------------------
#define CVT_BLOCKS 4096
__global__ void __launch_bounds__(256) prep_kernel(
    const float* __restrict__ x, const float* __restrict__ W,
    const float* __restrict__ lA, const float* __restrict__ lB,
    unsigned short* __restrict__ xb, unsigned short* __restrict__ awb) {
  __shared__ float Asub[16 * 512];
  __shared__ float Bsub[32 * 16];
  const int tid = threadIdx.x;

  if (blockIdx.x < 1024) {
    const int i0 = (blockIdx.x & 7) * 512;
    const int o0 = (blockIdx.x >> 3) * 32;
    for (int idx = tid; idx < 16 * 512; idx += 256) {
      int r = idx >> 9, i = idx & 511;
      Asub[idx] = lA[r * K_DIM + i0 + i];
    }
    for (int idx = tid; idx < 32 * 16; idx += 256) {
      int o = idx >> 4, r = idx & 15;
      Bsub[idx] = lB[(o0 + o) * R_DIM + r];
    }
    __syncthreads();
    for (int idx = tid; idx < 32 * 512; idx += 256) {
      int o = idx >> 9, i = idx & 511;
      float s = 1.0f;
#pragma unroll
      for (int r = 0; r < 16; ++r) s += Asub[r * 512 + i] * Bsub[o * 16 + r];
      size_t g = (size_t)(o0 + o) * K_DIM + i0 + i;
      awb[g] = f2bf(W[g] * s);
    }
  } else {
    const long total = (long)M_DIM * K_DIM;
    long i = ((long)(blockIdx.x - 1024) * 256 + tid) * 8;
    const long stride = (long)CVT_BLOCKS * 256 * 8;
    for (; i < total; i += stride) {
      const float4* p = (const float4*)(x + i);
      float4 f0 = p[0], f1 = p[1];
      u16x8 v;
      v[0] = f2bf(f0.x); v[1] = f2bf(f0.y); v[2] = f2bf(f0.z); v[3] = f2bf(f0.w);
      v[4] = f2bf(f1.x); v[5] = f2bf(f1.y); v[6] = f2bf(f1.z); v[7] = f2bf(f1.w);
      *(u16x8*)(xb + i) = v;
    }
  }
}

// ---------------------------------------------------------------------------
// GEMM: out[m,n] = sum_k xb[m,k]*awb[n,k] + bias[n]
// 256x256 tile, BK=64, 8 waves (2Mx4N). m201 8-phase schedule (R3 ledger)
// with TRUE counted waits: each phase = {ds_read subtile | stage | BAR |
// lgkm0 | sched0 | setprio1 16xMFMA setprio0 | BAR}; vmcnt(6) only at ph4/ph8.
// vmcnt FIFO (steady state, iter i, tiles t=2i buf0 / t+1 buf1):
//   entering ph1 leftover = {B(t+1) x4, A(t+1)h0 x2}
//   ph4 wait: 6+2(ph1 A(t+1)h1)+4(ph3 B(t+2))+2(ph4 A(t+2)h0)=14 -> vmcnt(6)
//     completes {B(t+1),A(t+1)h0,A(t+1)h1} = all of tile t+1 (used ph5-8).
//   ph8 wait symmetric: completes all of tile t+2 (used next ph1-4).
// Stage WAR ledger: every stage target's last ds_read is >=1 closing barrier
// earlier; gll writes land >=300cy after issue (R3-proven placements).
// ---------------------------------------------------------------------------
__global__ void __launch_bounds__(512, 2) gemm_kernel(
    const unsigned short* __restrict__ Ag,   // [M][K] bf16 bits (x)
    const unsigned short* __restrict__ Bg,   // [N][K] bf16 bits (adapted W)
    const float* __restrict__ bias,
    float* __restrict__ out) {
  __shared__ __attribute__((aligned(16))) unsigned short LDS[2 * 32768];

  // Bijective XCD swizzle: grid = 32*16 = 512, 512 % 8 == 0.
  const int nwg = gridDim.x;
  const int q8 = nwg >> 3;
  const int wg = blockIdx.x;
  const int swz = (wg & 7) * q8 + (wg >> 3);
  const int tiles_n = N_DIM / 256;           // 16
  const int brow = (swz / tiles_n) * 256;
  const int bcol = (swz % tiles_n) * 256;

  const int tid = threadIdx.x;
  const int lane = tid & 63;
  const int w = tid >> 6;                    // wave 0..7
  const int wr = w >> 2, wc = w & 3;         // 2 x 4 wave grid
  const int fr = lane & 15;
  const int kq = (lane >> 4) << 3;           // 0,8,16,24

  // staging source map (inverse of st_16x32 swizzle)
  const int rr = lane >> 2;
  const int cc = ((lane & 1) << 3) | ((((lane >> 1) ^ (lane >> 5)) & 1) << 4);
  const int c_sw = ((w & 1) << 5) | cc;
  const int rbase = ((w >> 1) << 4) + rr;

  const unsigned short* srcA[2][2];          // [half][q]
#pragma unroll
  for (int h = 0; h < 2; ++h)
#pragma unroll
    for (int q = 0; q < 2; ++q)
      srcA[h][q] = Ag + (size_t)(brow + h * 128 + q * 64 + rbase) * K_DIM + c_sw;
  const long long bdelta = (long long)(Bg - Ag) + (long long)(bcol - brow) * K_DIM;

  auto stageA = [&](int buf, int h, int kt) {
#pragma unroll
    for (int q = 0; q < 2; ++q)
      __builtin_amdgcn_global_load_lds(AS1(srcA[h][q] + (size_t)kt * 64),
          AS3(&LDS[buf * 32768 + h * 8192 + q * 4096 + w * 512]), 16, 0, 0);
  };
  auto stageB = [&](int buf, int h, int kt) {
#pragma unroll
    for (int q = 0; q < 2; ++q)
      __builtin_amdgcn_global_load_lds(AS1(srcA[h][q] + bdelta + (size_t)kt * 64),
          AS3(&LDS[buf * 32768 + 16384 + h * 8192 + q * 4096 + w * 512]), 16, 0, 0);
  };

  // swizzled ds_read addressing
  const int rdsw = ((fr << 6) | (kq << 1)) ^ ((fr & 8) << 2);
  auto lda = [&](int buf, int m, int kk) -> bf16x8 {
    return *(const bf16x8*)((const char*)LDS +
        (buf * 65536 + wr * 16384 + (m * 2 + kk) * 1024 + rdsw));
  };
  auto ldb = [&](int buf, int n, int kk) -> bf16x8 {
    return *(const bf16x8*)((const char*)LDS +
        (buf * 65536 + 32768 + (wc >> 1) * 16384 +
         (((wc & 1) * 4 + n) * 2 + kk) * 1024 + rdsw));
  };

  f32x4 acc[8][4] = {};
  bf16x8 a[2][4], b[2][4];

  auto load_a_group = [&](int buf, int mg) {   // 8 x ds_read_b128
#pragma unroll
    for (int kk = 0; kk < 2; ++kk)
#pragma unroll
      for (int mi = 0; mi < 4; ++mi)
        a[kk][mi] = lda(buf, mg + mi, kk);
  };
  auto load_b_pair = [&](int buf, int nb) {    // 4 x ds_read_b128
#pragma unroll
    for (int kk = 0; kk < 2; ++kk)
#pragma unroll
      for (int ni = 0; ni < 2; ++ni)
        b[kk][nb + ni] = ldb(buf, nb + ni, kk);
  };
  auto mma_quad = [&](int mb, int nb) {        // 16 x MFMA (one C-quadrant)
#pragma unroll
    for (int mi = 0; mi < 4; ++mi)
#pragma unroll
      for (int ni = 0; ni < 2; ++ni)
#pragma unroll
        for (int kk = 0; kk < 2; ++kk)
          acc[mb + mi][nb + ni] = __builtin_amdgcn_mfma_f32_16x16x32_bf16(
              a[kk][mi], b[kk][nb + ni], acc[mb + mi][nb + ni], 0, 0, 0);
  };

  // prologue: t0 full (8 gll) + t1.B0,B1,A0 (6 gll); counted wait leaves 6
  stageB(0, 0, 0); stageB(0, 1, 0); stageA(0, 0, 0); stageA(0, 1, 0);
  stageB(1, 0, 1); stageB(1, 1, 1); stageA(1, 0, 1);
  VMCNT6();
  BAR();

  // main loop: 2 K-tiles / iteration, 8 phases
#pragma unroll 1
  for (int i = 0; i < K_DIM / 128; ++i) {
    const bool more = (i < K_DIM / 128 - 1);
    const int t_cur1 = 2 * i + 1, t_nx0 = 2 * i + 2, t_nx1 = 2 * i + 3;

    // ===== K-tile 2i on buf0 =====
    // ph1: read A m0-3 + B n0-1 (12); stage buf1.A1 <- t_cur1
    load_a_group(0, 0); load_b_pair(0, 0);
    stageA(1, 1, t_cur1);
    LGKM8();
    BAR(); LGKM0(); SCHED0();
    __builtin_amdgcn_s_setprio(1); mma_quad(0, 0); __builtin_amdgcn_s_setprio(0);
    BAR();
    // ph2: read B n2-3
    load_b_pair(0, 2);
    BAR(); LGKM0(); SCHED0();
    __builtin_amdgcn_s_setprio(1); mma_quad(0, 2); __builtin_amdgcn_s_setprio(0);
    BAR();
    // ph3: read A m4-7; stage buf0.B <- t_nx0 (buf0.B last read in ph2)
    load_a_group(0, 4);
    if (more) { stageB(0, 0, t_nx0); stageB(0, 1, t_nx0); }
    BAR(); LGKM0(); SCHED0();
    __builtin_amdgcn_s_setprio(1); mma_quad(4, 2); __builtin_amdgcn_s_setprio(0);
    BAR();
    // ph4: stage buf0.A0 <- t_nx0 (buf0.A last read in ph3); vmcnt: t_cur1 lands
    if (more) stageA(0, 0, t_nx0);
    BAR();
    __builtin_amdgcn_s_setprio(1); mma_quad(4, 0); __builtin_amdgcn_s_setprio(0);
    if (more) { VMCNT6(); } else { VMCNT0(); }
    SCHED0();
    BAR();

    // ===== K-tile 2i+1 on buf1 =====
    // ph5: read A m0-3 + B n0-1; stage buf0.A1 <- t_nx0
    load_a_group(1, 0); load_b_pair(1, 0);
    if (more) stageA(0, 1, t_nx0);
    LGKM8();
    BAR(); LGKM0(); SCHED0();
    __builtin_amdgcn_s_setprio(1); mma_quad(0, 0); __builtin_amdgcn_s_setprio(0);
    BAR();
    // ph6: read B n2-3
    load_b_pair(1, 2);
    BAR(); LGKM0(); SCHED0();
    __builtin_amdgcn_s_setprio(1); mma_quad(0, 2); __builtin_amdgcn_s_setprio(0);
    BAR();
    // ph7: read A m4-7; stage buf1.B <- t_nx1 (buf1.B last read in ph6)
    load_a_group(1, 4);
    if (more) { stageB(1, 0, t_nx1); stageB(1, 1, t_nx1); }
    BAR(); LGKM0(); SCHED0();
    __builtin_amdgcn_s_setprio(1); mma_quad(4, 2); __builtin_amdgcn_s_setprio(0);
    BAR();
    // ph8: stage buf1.A0 <- t_nx1 (buf1.A last read in ph7); vmcnt: t_nx0 lands
    if (more) stageA(1, 0, t_nx1);
    BAR();
    __builtin_amdgcn_s_setprio(1); mma_quad(4, 0); __builtin_amdgcn_s_setprio(0);
    if (more) { VMCNT6(); SCHED0(); }
    BAR();
  }

  // epilogue: C/D map col = lane&15, row = (lane>>4)*4 + j
  const int fq = (lane >> 4) * 4;
#pragma unroll
  for (int n = 0; n < 4; ++n) {
    const int col = bcol + wc * 64 + n * 16 + fr;
    const float bb = bias[col];
#pragma unroll
    for (int m = 0; m < 8; ++m) {
      const int row = brow + wr * 128 + m * 16 + fq;
      f32x4 v = acc[m][n];
#pragma unroll
      for (int j = 0; j < 4; ++j)
        out[(size_t)(row + j) * N_DIM + col] = v[j] + bb;
    }
  }
}

// ---------------------------------------------------------------------------
extern "C" void kernel_launch(void* const* d_in, const int* in_sizes, int n_in,
                              void* d_out, int out_size, void* d_ws, size_t ws_size,
                              hipStream_t stream) {
  const float* x    = (const float*)d_in[0];
  const float* W    = (const float*)d_in[1];
  const float* bias = (const float*)d_in[2];
  const float* lA   = (const float*)d_in[3];
  const float* lB   = (const float*)d_in[4];
  float* out = (float*)d_out;

  unsigned short* xb  = (unsigned short*)d_ws;            // 64 MiB
  unsigned short* awb = xb + (size_t)M_DIM * K_DIM;       // 32 MiB

  prep_kernel<<<1024 + CVT_BLOCKS, 256, 0, stream>>>(x, W, lA, lB, xb, awb);
  gemm_kernel<<<(M_DIM / 256) * (N_DIM / 256), 512, 0, stream>>>(xb, awb, bias, out);
}